// Round 4
// baseline (724.747 us; speedup 1.0000x reference)
//
#include <hip/hip_runtime.h>
#include <hip/hip_fp16.h>
#include <hip/hip_cooperative_groups.h>

namespace cg = cooperative_groups;

#define N_NODES 50000
#define N_EDGES 800000

typedef _Float16 half8 __attribute__((ext_vector_type(8)));
typedef _Float16 f16x4 __attribute__((ext_vector_type(4)));
typedef float floatx4 __attribute__((ext_vector_type(4)));

// ===========================================================================
// Shared phase bodies (used by both the cooperative mega-kernel and the
// fallback per-phase kernels).
// ===========================================================================

// lin via MFMA 16x16x32 f16 (layout verified R8). 4 waves, 16 rows x 64 cols
// per wave, fragments direct from global. TIn=float folds the x cast in.
// Score epilogue stores E = exp(score) (deferred-normalization softmax).
template <typename TIn, int K>
__device__ __forceinline__ void lin_body(int vb, int t,
                                         const TIn* __restrict__ in,
                                         const _Float16* __restrict__ w,
                                         const float* __restrict__ b,
                                         const float* __restrict__ aw,
                                         _Float16* __restrict__ h,
                                         float2* __restrict__ s, int n) {
    const int l = t & 63;
    const int wv = t >> 6;
    const int arow = l & 15;
    const int kg = l >> 4;
    const long rowbase = (long)vb * 64 + wv * 16;
    long arow_g = rowbase + arow;
    if (arow_g >= n) arow_g = n - 1;

    floatx4 acc[4] = {};

    for (int kc = 0; kc < K; kc += 32) {
        const int ks = kc + kg * 8;
        half8 a;
        if (sizeof(TIn) == 4) {
            const TIn* ap = in + arow_g * K + ks;
            #pragma unroll
            for (int j = 0; j < 8; ++j) a[j] = (_Float16)ap[j];
        } else {
            a = *(const half8*)((const _Float16*)in + arow_g * K + ks);
        }
        #pragma unroll
        for (int ct = 0; ct < 4; ++ct) {
            half8 bb = *(const half8*)(w + (long)(ct * 16 + arow) * K + ks);
            acc[ct] = __builtin_amdgcn_mfma_f32_16x16x32_f16(a, bb, acc[ct], 0, 0, 0);
        }
    }

    const int c = l & 15;
    const int rq = l >> 4;
    float bias[4], a2c[4], a3c[4];
    #pragma unroll
    for (int ct = 0; ct < 4; ++ct) {
        int col = ct * 16 + c;
        bias[ct] = b[col];
        a2c[ct] = aw[2 * 128 + col] + aw[2 * 128 + 64 + col];
        a3c[ct] = aw[3 * 128 + col] + aw[3 * 128 + 64 + col];
    }
    #pragma unroll
    for (int r = 0; r < 4; ++r) {
        long row = rowbase + rq * 4 + r;
        bool ok = row < n;
        float q2 = 0.f, q3 = 0.f;
        _Float16 hv[4];
        #pragma unroll
        for (int ct = 0; ct < 4; ++ct) {
            float u = acc[ct][r] + bias[ct];
            u = u > 0.f ? u : 0.2f * u;
            q2 += u * a2c[ct];
            q3 += u * a3c[ct];
            hv[ct] = (_Float16)u;
        }
        if (ok) {
            #pragma unroll
            for (int ct = 0; ct < 4; ++ct) h[row * 64 + ct * 16 + c] = hv[ct];
        }
        #pragma unroll
        for (int o = 1; o < 16; o <<= 1) {
            q2 += __shfl_xor(q2, o);
            q3 += __shfl_xor(q3, o);
        }
        if (c == 0 && ok) s[row] = make_float2(__expf(q2), __expf(q3));
    }
}

// Fused layer: agg (QUARTER-PER-NODE) + next lin from LDS. Block = 16 nodes.
// lane q=l>>4 owns node vb*16+wv*4+q, fl=l&15 owns features fl*4..+3.
// E[dg] quarter-uniform -> every lane carries full S2/S3, zero merge shuffles.
// Non-final: g row -> LDS (stride 200 f16), then 16x64 lin (wave=col-slice),
// score via in-quarter xor-reduce + 4-wave LDS reduce. g never touches HBM.
// Barrier safety across vb iterations: iteration k+1's first LDS write is
// g_lds (pre-sync1), and sync1(k+1) orders iteration k's spart reads first.
template <int FINAL>
__device__ __forceinline__ void layer_body(int vb, int t,
                                           const _Float16* __restrict__ hfeat,
                                           const float2* __restrict__ E,
                                           const int* __restrict__ dst,
                                           const int* __restrict__ row_ptr,
                                           const _Float16* __restrict__ w,
                                           const float* __restrict__ b,
                                           const float* __restrict__ aw,
                                           _Float16* __restrict__ h_out,
                                           float2* __restrict__ s_out,
                                           float* __restrict__ out_f,
                                           _Float16 (*g_lds)[200],
                                           float2 (*spart)[16]) {
    const int l = t & 63;
    const int wv = t >> 6;
    const int q = l >> 4;      // phase A: node slot | phase B: k-group
    const int fl = l & 15;     // phase A: feature quad | phase B: row/col lane
    const int base = vb * 16;
    const int i = base + wv * 4 + q;           // N_NODES % 16 == 0 -> valid

    const int r0 = row_ptr[i];
    const int deg = row_ptr[i + 1] - r0;
    int md = deg;
    md = max(md, __shfl_xor(md, 16));
    md = max(md, __shfl_xor(md, 32));          // wave-uniform max degree

    float am[4] = {}, a2[4] = {}, a3[4] = {};
    float S2 = 0.f, S3 = 0.f;
    const int safew = deg > 0 ? r0 + deg - 1 : 0;   // clamp for padded lanes

    for (int c0 = 0; c0 < md; c0 += 16) {
        const int dl = dst[min(r0 + c0 + fl, safew)];  // 16 edge ids / quarter
        const int jn = min(16, md - c0);               // uniform inner bound
        for (int j = 0; j < jn; j += 4) {
            int dg[4]; float vm[4];
            #pragma unroll
            for (int g = 0; g < 4; ++g) {
                const int sl = j + g;                  // <= 15 always
                dg[g] = __shfl(dl, (q << 4) | sl);     // broadcast in-quarter
                vm[g] = (c0 + sl < deg) ? 1.f : 0.f;
            }
            f16x4 hv[4]; float2 Ev[4];
            #pragma unroll
            for (int g = 0; g < 4; ++g) {
                hv[g] = *(const f16x4*)(hfeat + (long)dg[g] * 64 + fl * 4);
                Ev[g] = E[dg[g]];                      // quarter-uniform bcast
            }
            #pragma unroll
            for (int g = 0; g < 4; ++g) {
                const float e2 = vm[g] * Ev[g].x, e3 = vm[g] * Ev[g].y;
                S2 += e2; S3 += e3;
                #pragma unroll
                for (int k = 0; k < 4; ++k) {
                    const float hf = (float)hv[g][k];
                    am[k] += vm[g] * hf;
                    a2[k] += e2 * hf;
                    a3[k] += e3 * hf;
                }
            }
        }
    }

    const float inv_deg = deg > 0 ? 1.f / (float)deg : 0.f;
    const float i2 = deg > 0 ? 1.f / S2 : 0.f;
    const float i3 = deg > 0 ? 1.f / S3 : 0.f;

    if (FINAL) {
        floatx4 o;
        #pragma unroll
        for (int k = 0; k < 4; ++k)
            o[k] = fmaxf(0.5f * inv_deg * am[k] + 0.25f * (a2[k] * i2 + a3[k] * i3), 0.f);
        *(floatx4*)(out_f + (long)i * 64 + fl * 4) = o;
        return;
    }

    // g row into LDS (all 16 lanes of the quarter write their own quads)
    {
        const int nl = wv * 4 + q;
        f16x4 o0, o1, o2;
        #pragma unroll
        for (int k = 0; k < 4; ++k) {
            o0[k] = (_Float16)fmaxf(am[k] * inv_deg, 0.f);
            o1[k] = (_Float16)fmaxf(a2[k] * i2, 0.f);
            o2[k] = (_Float16)fmaxf(a3[k] * i3, 0.f);
        }
        *(f16x4*)(&g_lds[nl][fl * 4])       = o0;
        *(f16x4*)(&g_lds[nl][64 + fl * 4])  = o1;
        *(f16x4*)(&g_lds[nl][128 + fl * 4]) = o2;
    }
    __syncthreads();

    // Phase B: lin for these 16 rows. Wave wv = cols wv*16..wv*16+15.
    floatx4 acc = {};
    #pragma unroll
    for (int kc = 0; kc < 192; kc += 32) {
        const int ks = kc + q * 8;
        half8 a = *(const half8*)(&g_lds[fl][ks]);
        half8 bb = *(const half8*)(w + (long)(wv * 16 + fl) * 192 + ks);
        acc = __builtin_amdgcn_mfma_f32_16x16x32_f16(a, bb, acc, 0, 0, 0);
    }

    const int col = wv * 16 + fl;
    const float bias = b[col];
    const float a2c = aw[2 * 128 + col] + aw[2 * 128 + 64 + col];
    const float a3c = aw[3 * 128 + col] + aw[3 * 128 + 64 + col];
    #pragma unroll
    for (int r = 0; r < 4; ++r) {
        const int row = q * 4 + r;
        float u = acc[r] + bias;
        u = u > 0.f ? u : 0.2f * u;
        h_out[(long)(base + row) * 64 + col] = (_Float16)u;
        float q2 = u * a2c, q3 = u * a3c;
        #pragma unroll
        for (int o = 1; o < 16; o <<= 1) {
            q2 += __shfl_xor(q2, o);
            q3 += __shfl_xor(q3, o);
        }
        if (fl == 0) spart[wv][row] = make_float2(q2, q3);
    }
    __syncthreads();
    if (t < 16) {
        const float2 p0 = spart[0][t], p1 = spart[1][t], p2 = spart[2][t], p3 = spart[3][t];
        s_out[base + t] = make_float2(__expf(p0.x + p1.x + p2.x + p3.x),
                                      __expf(p0.y + p1.y + p2.y + p3.y));
    }
}

// Setup work items (strided): row_ptr lower_bound; lw0 cast; lw1/lw2 fold
// (64x256 fp32) -> planar K=192 fp16 [o, ch*64+f], ch {0:h0+h1, 1:a2, 2:a3}.
__device__ __forceinline__ void setup_body(int gid, int gstride,
                                           const int* __restrict__ src,
                                           int* __restrict__ row_ptr,
                                           const float* __restrict__ lw0,
                                           const float* __restrict__ lw1,
                                           const float* __restrict__ lw2,
                                           _Float16* __restrict__ w0p,
                                           _Float16* __restrict__ w1p,
                                           _Float16* __restrict__ w2p) {
    for (int idx = gid; idx <= N_NODES; idx += gstride) {
        int lo = 0, hi = N_EDGES;
        while (lo < hi) {
            int mid = (lo + hi) >> 1;
            if (src[mid] < idx) lo = mid + 1; else hi = mid;
        }
        row_ptr[idx] = lo;
    }
    for (int idx = gid; idx < 64 * 128; idx += gstride) w0p[idx] = (_Float16)lw0[idx];
    for (int idx = gid; idx < 64 * 192; idx += gstride) {
        int o = idx / 192, r = idx % 192;
        int ch = r >> 6, f = r & 63;
        float v1, v2;
        if (ch == 0) {
            v1 = lw1[o * 256 + f * 4 + 0] + lw1[o * 256 + f * 4 + 1];
            v2 = lw2[o * 256 + f * 4 + 0] + lw2[o * 256 + f * 4 + 1];
        } else if (ch == 1) {
            v1 = lw1[o * 256 + f * 4 + 2];
            v2 = lw2[o * 256 + f * 4 + 2];
        } else {
            v1 = lw1[o * 256 + f * 4 + 3];
            v2 = lw2[o * 256 + f * 4 + 3];
        }
        w1p[idx] = (_Float16)v1;
        w2p[idx] = (_Float16)v2;
    }
}

// ===========================================================================
// Cooperative mega-kernel: setup -> lin0 -> layer0 -> layer1 -> final,
// grid.sync() between phases. R15: grid sized at runtime to the TRUE
// co-residency limit (R14's 768 = 36% occupancy was the 2.4x slowdown;
// latency-bound gathers scale ~1/occupancy). (256,8) holds the 64-VGPR line
// so 8 blocks/CU fit -> 2048 blocks expected.
// ===========================================================================
__global__ __launch_bounds__(256, 8) void fused_all(
    const float* __restrict__ x,
    const float* __restrict__ lw0, const float* __restrict__ lb0, const float* __restrict__ aw0,
    const float* __restrict__ lw1, const float* __restrict__ lb1, const float* __restrict__ aw1,
    const float* __restrict__ lw2, const float* __restrict__ lb2, const float* __restrict__ aw2,
    const int* __restrict__ src, const int* __restrict__ dst,
    float* __restrict__ out,
    _Float16* __restrict__ hA, _Float16* __restrict__ hB,
    float2* __restrict__ sA, float2* __restrict__ sB,
    _Float16* __restrict__ w0p, _Float16* __restrict__ w1p, _Float16* __restrict__ w2p,
    int* __restrict__ row_ptr) {
    __shared__ _Float16 g_lds[16][200];
    __shared__ float2 spart[4][16];

    cg::grid_group grid = cg::this_grid();
    const int t = threadIdx.x;
    const int gs = gridDim.x;
    const int gid = blockIdx.x * 256 + t;

    setup_body(gid, gs * 256, src, row_ptr, lw0, lw1, lw2, w0p, w1p, w2p);
    grid.sync();

    const int lin_vbs = (N_NODES + 63) / 64;     // 782
    for (int vb = blockIdx.x; vb < lin_vbs; vb += gs)
        lin_body<float, 128>(vb, t, x, w0p, lb0, aw0, hA, sA, N_NODES);
    grid.sync();

    const int layer_vbs = N_NODES / 16;          // 3125
    for (int vb = blockIdx.x; vb < layer_vbs; vb += gs)
        layer_body<0>(vb, t, hA, sA, dst, row_ptr, w1p, lb1, aw1, hB, sB, out, g_lds, spart);
    grid.sync();

    for (int vb = blockIdx.x; vb < layer_vbs; vb += gs)
        layer_body<0>(vb, t, hB, sB, dst, row_ptr, w2p, lb2, aw2, hA, sA, out, g_lds, spart);
    grid.sync();

    for (int vb = blockIdx.x; vb < layer_vbs; vb += gs)
        layer_body<1>(vb, t, hA, sA, dst, row_ptr, w2p, lb2, aw2, hB, sB, out, g_lds, spart);
}

// ===========================================================================
// Fallback per-phase kernels (used only if cooperative launch fails).
// ===========================================================================
__global__ __launch_bounds__(256) void setup_kernel(const int* __restrict__ src,
                                                    int* __restrict__ row_ptr,
                                                    const float* __restrict__ lw0,
                                                    const float* __restrict__ lw1,
                                                    const float* __restrict__ lw2,
                                                    _Float16* __restrict__ w0p,
                                                    _Float16* __restrict__ w1p,
                                                    _Float16* __restrict__ w2p) {
    setup_body(blockIdx.x * 256 + threadIdx.x, gridDim.x * 256,
               src, row_ptr, lw0, lw1, lw2, w0p, w1p, w2p);
}

template <typename TIn, int K>
__global__ __launch_bounds__(256) void lin_kernel(const TIn* __restrict__ in,
                                                  const _Float16* __restrict__ w,
                                                  const float* __restrict__ b,
                                                  const float* __restrict__ aw,
                                                  _Float16* __restrict__ h,
                                                  float2* __restrict__ s, int n) {
    lin_body<TIn, K>(blockIdx.x, threadIdx.x, in, w, b, aw, h, s, n);
}

template <int FINAL>
__global__ __launch_bounds__(256) void layer_kernel(const _Float16* __restrict__ hfeat,
                                                    const float2* __restrict__ E,
                                                    const int* __restrict__ dst,
                                                    const int* __restrict__ row_ptr,
                                                    const _Float16* __restrict__ w,
                                                    const float* __restrict__ b,
                                                    const float* __restrict__ aw,
                                                    _Float16* __restrict__ h_out,
                                                    float2* __restrict__ s_out,
                                                    float* __restrict__ out_f) {
    __shared__ _Float16 g_lds[16][200];
    __shared__ float2 spart[4][16];
    layer_body<FINAL>(blockIdx.x, threadIdx.x, hfeat, E, dst, row_ptr, w, b, aw,
                      h_out, s_out, out_f, g_lds, spart);
}

// ---------------------------------------------------------------------------
extern "C" void kernel_launch(void* const* d_in, const int* in_sizes, int n_in,
                              void* d_out, int out_size, void* d_ws, size_t ws_size,
                              hipStream_t stream) {
    const float* x = (const float*)d_in[0];
    const float* lw0 = (const float*)d_in[1];
    const float* lb0 = (const float*)d_in[2];
    const float* aw0 = (const float*)d_in[3];
    const float* lw1 = (const float*)d_in[5];
    const float* lb1 = (const float*)d_in[6];
    const float* aw1 = (const float*)d_in[7];
    const float* lw2 = (const float*)d_in[9];
    const float* lb2 = (const float*)d_in[10];
    const float* aw2 = (const float*)d_in[11];
    const int* src = (const int*)d_in[13];
    const int* dst = (const int*)d_in[14];
    float* out = (float*)d_out;

    const int N = N_NODES;

    // ws layout: hA,hB: N*64 f16 | sA,sB: N float2
    //            | w0p 64*128 f16 | w1p,w2p 64*192 f16 | row_ptr N+1 int
    _Float16* hA = (_Float16*)d_ws;
    _Float16* hB = hA + (size_t)N * 64;
    float2* sA = (float2*)(hB + (size_t)N * 64);
    float2* sB = sA + N;
    _Float16* w0p = (_Float16*)(sB + N);
    _Float16* w1p = w0p + 64 * 128;
    _Float16* w2p = w1p + 64 * 192;
    int* row_ptr = (int*)(w2p + 64 * 192);

    // Runtime co-residency limit (host-side queries; graph-capture-safe).
    int coop_grid = 768;                      // known-working conservative floor
    int blocks_per_cu = 0;
    if (hipOccupancyMaxActiveBlocksPerMultiprocessor(
            &blocks_per_cu, (const void*)fused_all, 256, 0) == hipSuccess &&
        blocks_per_cu > 0) {
        int num_cu = 0, dev = 0;
        hipGetDevice(&dev);
        if (hipDeviceGetAttribute(&num_cu, hipDeviceAttributeMultiprocessorCount,
                                  dev) == hipSuccess && num_cu > 0) {
            long g = (long)blocks_per_cu * num_cu;
            coop_grid = (int)(g > 3125 ? 3125 : g);   // >= vbs is pointless
        }
    }

    void* kargs[] = {&x, &lw0, &lb0, &aw0, &lw1, &lb1, &aw1, &lw2, &lb2, &aw2,
                     &src, &dst, &out, &hA, &hB, &sA, &sB, &w0p, &w1p, &w2p, &row_ptr};

    hipError_t err = hipLaunchCooperativeKernel((const void*)fused_all,
                                                dim3(coop_grid), dim3(256),
                                                kargs, 0, stream);
    if (err == hipSuccess) return;
    (void)hipGetLastError();   // clear sticky error; fall back to 5 dispatches

    const int lin_grid = (N + 63) / 64;      // 782
    const int layer_grid = N / 16;           // 3125

    setup_kernel<<<196, 256, 0, stream>>>(src, row_ptr, lw0, lw1, lw2, w0p, w1p, w2p);
    lin_kernel<float, 128><<<lin_grid, 256, 0, stream>>>(x, w0p, lb0, aw0, hA, sA, N);
    layer_kernel<0><<<layer_grid, 256, 0, stream>>>(hA, sA, dst, row_ptr, w1p, lb1, aw1, hB, sB, out);
    layer_kernel<0><<<layer_grid, 256, 0, stream>>>(hB, sB, dst, row_ptr, w2p, lb2, aw2, hA, sA, out);
    layer_kernel<1><<<layer_grid, 256, 0, stream>>>(hA, sA, dst, row_ptr, w2p, lb2, aw2, hB, sB, out);
}

// Round 5
// 202.329 us; speedup vs baseline: 3.5820x; 3.5820x over previous
//
#include <hip/hip_runtime.h>
#include <hip/hip_fp16.h>
#include <hip/hip_cooperative_groups.h>

namespace cg = cooperative_groups;

#define N_NODES 50000
#define N_EDGES 800000

typedef _Float16 half8 __attribute__((ext_vector_type(8)));
typedef _Float16 f16x4 __attribute__((ext_vector_type(4)));
typedef float floatx4 __attribute__((ext_vector_type(4)));

// ===========================================================================
// Shared phase bodies (used by both the cooperative mega-kernel and the
// fallback per-phase kernels).
// ===========================================================================

// lin via MFMA 16x16x32 f16 (layout verified R8). 4 waves, 16 rows x 64 cols
// per wave, fragments direct from global. TIn=float folds the x cast in.
// Score epilogue stores E = exp(score) (deferred-normalization softmax).
template <typename TIn, int K>
__device__ __forceinline__ void lin_body(int vb, int t,
                                         const TIn* __restrict__ in,
                                         const _Float16* __restrict__ w,
                                         const float* __restrict__ b,
                                         const float* __restrict__ aw,
                                         _Float16* __restrict__ h,
                                         float2* __restrict__ s, int n) {
    const int l = t & 63;
    const int wv = t >> 6;
    const int arow = l & 15;
    const int kg = l >> 4;
    const long rowbase = (long)vb * 64 + wv * 16;
    long arow_g = rowbase + arow;
    if (arow_g >= n) arow_g = n - 1;

    floatx4 acc[4] = {};

    for (int kc = 0; kc < K; kc += 32) {
        const int ks = kc + kg * 8;
        half8 a;
        if (sizeof(TIn) == 4) {
            const TIn* ap = in + arow_g * K + ks;
            #pragma unroll
            for (int j = 0; j < 8; ++j) a[j] = (_Float16)ap[j];
        } else {
            a = *(const half8*)((const _Float16*)in + arow_g * K + ks);
        }
        #pragma unroll
        for (int ct = 0; ct < 4; ++ct) {
            half8 bb = *(const half8*)(w + (long)(ct * 16 + arow) * K + ks);
            acc[ct] = __builtin_amdgcn_mfma_f32_16x16x32_f16(a, bb, acc[ct], 0, 0, 0);
        }
    }

    const int c = l & 15;
    const int rq = l >> 4;
    float bias[4], a2c[4], a3c[4];
    #pragma unroll
    for (int ct = 0; ct < 4; ++ct) {
        int col = ct * 16 + c;
        bias[ct] = b[col];
        a2c[ct] = aw[2 * 128 + col] + aw[2 * 128 + 64 + col];
        a3c[ct] = aw[3 * 128 + col] + aw[3 * 128 + 64 + col];
    }
    #pragma unroll
    for (int r = 0; r < 4; ++r) {
        long row = rowbase + rq * 4 + r;
        bool ok = row < n;
        float q2 = 0.f, q3 = 0.f;
        _Float16 hv[4];
        #pragma unroll
        for (int ct = 0; ct < 4; ++ct) {
            float u = acc[ct][r] + bias[ct];
            u = u > 0.f ? u : 0.2f * u;
            q2 += u * a2c[ct];
            q3 += u * a3c[ct];
            hv[ct] = (_Float16)u;
        }
        if (ok) {
            #pragma unroll
            for (int ct = 0; ct < 4; ++ct) h[row * 64 + ct * 16 + c] = hv[ct];
        }
        #pragma unroll
        for (int o = 1; o < 16; o <<= 1) {
            q2 += __shfl_xor(q2, o);
            q3 += __shfl_xor(q3, o);
        }
        if (c == 0 && ok) s[row] = make_float2(__expf(q2), __expf(q3));
    }
}

// Fused layer: agg (QUARTER-PER-NODE) + next lin from LDS. Block = 16 nodes.
// lane q=l>>4 owns node vb*16+wv*4+q, fl=l&15 owns features fl*4..+3.
// E[dg] quarter-uniform -> every lane carries full S2/S3, zero merge shuffles.
// Non-final: g row -> LDS (stride 200 f16), then 16x64 lin (wave=col-slice),
// score via in-quarter xor-reduce + 4-wave LDS reduce. g never touches HBM.
// Barrier safety across vb iterations: iteration k+1's first LDS write is
// g_lds (pre-sync1), and sync1(k+1) orders iteration k's spart reads first.
template <int FINAL>
__device__ __forceinline__ void layer_body(int vb, int t,
                                           const _Float16* __restrict__ hfeat,
                                           const float2* __restrict__ E,
                                           const int* __restrict__ dst,
                                           const int* __restrict__ row_ptr,
                                           const _Float16* __restrict__ w,
                                           const float* __restrict__ b,
                                           const float* __restrict__ aw,
                                           _Float16* __restrict__ h_out,
                                           float2* __restrict__ s_out,
                                           float* __restrict__ out_f,
                                           _Float16 (*g_lds)[200],
                                           float2 (*spart)[16]) {
    const int l = t & 63;
    const int wv = t >> 6;
    const int q = l >> 4;      // phase A: node slot | phase B: k-group
    const int fl = l & 15;     // phase A: feature quad | phase B: row/col lane
    const int base = vb * 16;
    const int i = base + wv * 4 + q;           // N_NODES % 16 == 0 -> valid

    const int r0 = row_ptr[i];
    const int deg = row_ptr[i + 1] - r0;
    int md = deg;
    md = max(md, __shfl_xor(md, 16));
    md = max(md, __shfl_xor(md, 32));          // wave-uniform max degree

    float am[4] = {}, a2[4] = {}, a3[4] = {};
    float S2 = 0.f, S3 = 0.f;
    const int safew = deg > 0 ? r0 + deg - 1 : 0;   // clamp for padded lanes

    for (int c0 = 0; c0 < md; c0 += 16) {
        const int dl = dst[min(r0 + c0 + fl, safew)];  // 16 edge ids / quarter
        const int jn = min(16, md - c0);               // uniform inner bound
        for (int j = 0; j < jn; j += 4) {
            int dg[4]; float vm[4];
            #pragma unroll
            for (int g = 0; g < 4; ++g) {
                const int sl = j + g;                  // <= 15 always
                dg[g] = __shfl(dl, (q << 4) | sl);     // broadcast in-quarter
                vm[g] = (c0 + sl < deg) ? 1.f : 0.f;
            }
            f16x4 hv[4]; float2 Ev[4];
            #pragma unroll
            for (int g = 0; g < 4; ++g) {
                hv[g] = *(const f16x4*)(hfeat + (long)dg[g] * 64 + fl * 4);
                Ev[g] = E[dg[g]];                      // quarter-uniform bcast
            }
            #pragma unroll
            for (int g = 0; g < 4; ++g) {
                const float e2 = vm[g] * Ev[g].x, e3 = vm[g] * Ev[g].y;
                S2 += e2; S3 += e3;
                #pragma unroll
                for (int k = 0; k < 4; ++k) {
                    const float hf = (float)hv[g][k];
                    am[k] += vm[g] * hf;
                    a2[k] += e2 * hf;
                    a3[k] += e3 * hf;
                }
            }
        }
    }

    const float inv_deg = deg > 0 ? 1.f / (float)deg : 0.f;
    const float i2 = deg > 0 ? 1.f / S2 : 0.f;
    const float i3 = deg > 0 ? 1.f / S3 : 0.f;

    if (FINAL) {
        floatx4 o;
        #pragma unroll
        for (int k = 0; k < 4; ++k)
            o[k] = fmaxf(0.5f * inv_deg * am[k] + 0.25f * (a2[k] * i2 + a3[k] * i3), 0.f);
        *(floatx4*)(out_f + (long)i * 64 + fl * 4) = o;
        return;
    }

    // g row into LDS (all 16 lanes of the quarter write their own quads)
    {
        const int nl = wv * 4 + q;
        f16x4 o0, o1, o2;
        #pragma unroll
        for (int k = 0; k < 4; ++k) {
            o0[k] = (_Float16)fmaxf(am[k] * inv_deg, 0.f);
            o1[k] = (_Float16)fmaxf(a2[k] * i2, 0.f);
            o2[k] = (_Float16)fmaxf(a3[k] * i3, 0.f);
        }
        *(f16x4*)(&g_lds[nl][fl * 4])       = o0;
        *(f16x4*)(&g_lds[nl][64 + fl * 4])  = o1;
        *(f16x4*)(&g_lds[nl][128 + fl * 4]) = o2;
    }
    __syncthreads();

    // Phase B: lin for these 16 rows. Wave wv = cols wv*16..wv*16+15.
    floatx4 acc = {};
    #pragma unroll
    for (int kc = 0; kc < 192; kc += 32) {
        const int ks = kc + q * 8;
        half8 a = *(const half8*)(&g_lds[fl][ks]);
        half8 bb = *(const half8*)(w + (long)(wv * 16 + fl) * 192 + ks);
        acc = __builtin_amdgcn_mfma_f32_16x16x32_f16(a, bb, acc, 0, 0, 0);
    }

    const int col = wv * 16 + fl;
    const float bias = b[col];
    const float a2c = aw[2 * 128 + col] + aw[2 * 128 + 64 + col];
    const float a3c = aw[3 * 128 + col] + aw[3 * 128 + 64 + col];
    #pragma unroll
    for (int r = 0; r < 4; ++r) {
        const int row = q * 4 + r;
        float u = acc[r] + bias;
        u = u > 0.f ? u : 0.2f * u;
        h_out[(long)(base + row) * 64 + col] = (_Float16)u;
        float q2 = u * a2c, q3 = u * a3c;
        #pragma unroll
        for (int o = 1; o < 16; o <<= 1) {
            q2 += __shfl_xor(q2, o);
            q3 += __shfl_xor(q3, o);
        }
        if (fl == 0) spart[wv][row] = make_float2(q2, q3);
    }
    __syncthreads();
    if (t < 16) {
        const float2 p0 = spart[0][t], p1 = spart[1][t], p2 = spart[2][t], p3 = spart[3][t];
        s_out[base + t] = make_float2(__expf(p0.x + p1.x + p2.x + p3.x),
                                      __expf(p0.y + p1.y + p2.y + p3.y));
    }
}

// Setup work items (strided): row_ptr lower_bound; lw0 cast; lw1/lw2 fold
// (64x256 fp32) -> planar K=192 fp16 [o, ch*64+f], ch {0:h0+h1, 1:a2, 2:a3}.
__device__ __forceinline__ void setup_body(int gid, int gstride,
                                           const int* __restrict__ src,
                                           int* __restrict__ row_ptr,
                                           const float* __restrict__ lw0,
                                           const float* __restrict__ lw1,
                                           const float* __restrict__ lw2,
                                           _Float16* __restrict__ w0p,
                                           _Float16* __restrict__ w1p,
                                           _Float16* __restrict__ w2p) {
    for (int idx = gid; idx <= N_NODES; idx += gstride) {
        int lo = 0, hi = N_EDGES;
        while (lo < hi) {
            int mid = (lo + hi) >> 1;
            if (src[mid] < idx) lo = mid + 1; else hi = mid;
        }
        row_ptr[idx] = lo;
    }
    for (int idx = gid; idx < 64 * 128; idx += gstride) w0p[idx] = (_Float16)lw0[idx];
    for (int idx = gid; idx < 64 * 192; idx += gstride) {
        int o = idx / 192, r = idx % 192;
        int ch = r >> 6, f = r & 63;
        float v1, v2;
        if (ch == 0) {
            v1 = lw1[o * 256 + f * 4 + 0] + lw1[o * 256 + f * 4 + 1];
            v2 = lw2[o * 256 + f * 4 + 0] + lw2[o * 256 + f * 4 + 1];
        } else if (ch == 1) {
            v1 = lw1[o * 256 + f * 4 + 2];
            v2 = lw2[o * 256 + f * 4 + 2];
        } else {
            v1 = lw1[o * 256 + f * 4 + 3];
            v2 = lw2[o * 256 + f * 4 + 3];
        }
        w1p[idx] = (_Float16)v1;
        w2p[idx] = (_Float16)v2;
    }
}

// ===========================================================================
// Cooperative mega-kernel: setup -> lin0 -> layer0 -> layer1 -> final,
// grid.sync() between phases.
// R16: launch_bounds back to (256,4) — R15's (256,8) forced VGPR 64->32 and
// spilled the accumulator state to scratch (WRITE_SIZE 35->180MB, VALUBusy
// 5%, 2.2x slower). (256,4) compiles to 64 VGPR naturally, which already
// permits 8 blocks/CU; the runtime occupancy query sizes the grid to that.
// ===========================================================================
__global__ __launch_bounds__(256, 4) void fused_all(
    const float* __restrict__ x,
    const float* __restrict__ lw0, const float* __restrict__ lb0, const float* __restrict__ aw0,
    const float* __restrict__ lw1, const float* __restrict__ lb1, const float* __restrict__ aw1,
    const float* __restrict__ lw2, const float* __restrict__ lb2, const float* __restrict__ aw2,
    const int* __restrict__ src, const int* __restrict__ dst,
    float* __restrict__ out,
    _Float16* __restrict__ hA, _Float16* __restrict__ hB,
    float2* __restrict__ sA, float2* __restrict__ sB,
    _Float16* __restrict__ w0p, _Float16* __restrict__ w1p, _Float16* __restrict__ w2p,
    int* __restrict__ row_ptr) {
    __shared__ _Float16 g_lds[16][200];
    __shared__ float2 spart[4][16];

    cg::grid_group grid = cg::this_grid();
    const int t = threadIdx.x;
    const int gs = gridDim.x;
    const int gid = blockIdx.x * 256 + t;

    setup_body(gid, gs * 256, src, row_ptr, lw0, lw1, lw2, w0p, w1p, w2p);
    grid.sync();

    const int lin_vbs = (N_NODES + 63) / 64;     // 782
    for (int vb = blockIdx.x; vb < lin_vbs; vb += gs)
        lin_body<float, 128>(vb, t, x, w0p, lb0, aw0, hA, sA, N_NODES);
    grid.sync();

    const int layer_vbs = N_NODES / 16;          // 3125
    for (int vb = blockIdx.x; vb < layer_vbs; vb += gs)
        layer_body<0>(vb, t, hA, sA, dst, row_ptr, w1p, lb1, aw1, hB, sB, out, g_lds, spart);
    grid.sync();

    for (int vb = blockIdx.x; vb < layer_vbs; vb += gs)
        layer_body<0>(vb, t, hB, sB, dst, row_ptr, w2p, lb2, aw2, hA, sA, out, g_lds, spart);
    grid.sync();

    for (int vb = blockIdx.x; vb < layer_vbs; vb += gs)
        layer_body<1>(vb, t, hA, sA, dst, row_ptr, w2p, lb2, aw2, hB, sB, out, g_lds, spart);
}

// ===========================================================================
// Fallback per-phase kernels (used if cooperative launch fails or the
// queried co-residency is too low to be profitable).
// ===========================================================================
__global__ __launch_bounds__(256) void setup_kernel(const int* __restrict__ src,
                                                    int* __restrict__ row_ptr,
                                                    const float* __restrict__ lw0,
                                                    const float* __restrict__ lw1,
                                                    const float* __restrict__ lw2,
                                                    _Float16* __restrict__ w0p,
                                                    _Float16* __restrict__ w1p,
                                                    _Float16* __restrict__ w2p) {
    setup_body(blockIdx.x * 256 + threadIdx.x, gridDim.x * 256,
               src, row_ptr, lw0, lw1, lw2, w0p, w1p, w2p);
}

template <typename TIn, int K>
__global__ __launch_bounds__(256) void lin_kernel(const TIn* __restrict__ in,
                                                  const _Float16* __restrict__ w,
                                                  const float* __restrict__ b,
                                                  const float* __restrict__ aw,
                                                  _Float16* __restrict__ h,
                                                  float2* __restrict__ s, int n) {
    lin_body<TIn, K>(blockIdx.x, threadIdx.x, in, w, b, aw, h, s, n);
}

template <int FINAL>
__global__ __launch_bounds__(256) void layer_kernel(const _Float16* __restrict__ hfeat,
                                                    const float2* __restrict__ E,
                                                    const int* __restrict__ dst,
                                                    const int* __restrict__ row_ptr,
                                                    const _Float16* __restrict__ w,
                                                    const float* __restrict__ b,
                                                    const float* __restrict__ aw,
                                                    _Float16* __restrict__ h_out,
                                                    float2* __restrict__ s_out,
                                                    float* __restrict__ out_f) {
    __shared__ _Float16 g_lds[16][200];
    __shared__ float2 spart[4][16];
    layer_body<FINAL>(blockIdx.x, threadIdx.x, hfeat, E, dst, row_ptr, w, b, aw,
                      h_out, s_out, out_f, g_lds, spart);
}

// ---------------------------------------------------------------------------
extern "C" void kernel_launch(void* const* d_in, const int* in_sizes, int n_in,
                              void* d_out, int out_size, void* d_ws, size_t ws_size,
                              hipStream_t stream) {
    const float* x = (const float*)d_in[0];
    const float* lw0 = (const float*)d_in[1];
    const float* lb0 = (const float*)d_in[2];
    const float* aw0 = (const float*)d_in[3];
    const float* lw1 = (const float*)d_in[5];
    const float* lb1 = (const float*)d_in[6];
    const float* aw1 = (const float*)d_in[7];
    const float* lw2 = (const float*)d_in[9];
    const float* lb2 = (const float*)d_in[10];
    const float* aw2 = (const float*)d_in[11];
    const int* src = (const int*)d_in[13];
    const int* dst = (const int*)d_in[14];
    float* out = (float*)d_out;

    const int N = N_NODES;

    // ws layout: hA,hB: N*64 f16 | sA,sB: N float2
    //            | w0p 64*128 f16 | w1p,w2p 64*192 f16 | row_ptr N+1 int
    _Float16* hA = (_Float16*)d_ws;
    _Float16* hB = hA + (size_t)N * 64;
    float2* sA = (float2*)(hB + (size_t)N * 64);
    float2* sB = sA + N;
    _Float16* w0p = (_Float16*)(sB + N);
    _Float16* w1p = w0p + 64 * 128;
    _Float16* w2p = w1p + 64 * 192;
    int* row_ptr = (int*)(w2p + 64 * 192);

    // Runtime co-residency limit (host-side queries; graph-capture-safe).
    // R16: only take the coop path at >=5 blocks/CU — R14 proved coop at 3/CU
    // (36% occupancy) is a 2.4x regression vs the 5-dispatch fallback.
    int coop_grid = 0;
    int blocks_per_cu = 0;
    if (hipOccupancyMaxActiveBlocksPerMultiprocessor(
            &blocks_per_cu, (const void*)fused_all, 256, 0) == hipSuccess &&
        blocks_per_cu >= 5) {
        int num_cu = 0, dev = 0;
        hipGetDevice(&dev);
        if (hipDeviceGetAttribute(&num_cu, hipDeviceAttributeMultiprocessorCount,
                                  dev) == hipSuccess && num_cu > 0) {
            long g = (long)blocks_per_cu * num_cu;
            coop_grid = (int)(g > 3125 ? 3125 : g);   // >= vbs is pointless
        }
    }

    if (coop_grid > 0) {
        void* kargs[] = {&x, &lw0, &lb0, &aw0, &lw1, &lb1, &aw1, &lw2, &lb2, &aw2,
                         &src, &dst, &out, &hA, &hB, &sA, &sB, &w0p, &w1p, &w2p, &row_ptr};
        hipError_t err = hipLaunchCooperativeKernel((const void*)fused_all,
                                                    dim3(coop_grid), dim3(256),
                                                    kargs, 0, stream);
        if (err == hipSuccess) return;
        (void)hipGetLastError();   // clear sticky error; fall back
    }

    const int lin_grid = (N + 63) / 64;      // 782
    const int layer_grid = N / 16;           // 3125

    setup_kernel<<<196, 256, 0, stream>>>(src, row_ptr, lw0, lw1, lw2, w0p, w1p, w2p);
    lin_kernel<float, 128><<<lin_grid, 256, 0, stream>>>(x, w0p, lb0, aw0, hA, sA, N);
    layer_kernel<0><<<layer_grid, 256, 0, stream>>>(hA, sA, dst, row_ptr, w1p, lb1, aw1, hB, sB, out);
    layer_kernel<0><<<layer_grid, 256, 0, stream>>>(hB, sB, dst, row_ptr, w2p, lb2, aw2, hA, sA, out);
    layer_kernel<1><<<layer_grid, 256, 0, stream>>>(hA, sA, dst, row_ptr, w2p, lb2, aw2, hB, sB, out);
}